// Round 5
// baseline (89.128 us; speedup 1.0000x reference)
//
#include <hip/hip_runtime.h>
#include <hip/hip_bf16.h>

#define NN 4096
#define DD 512
#define TILE 128
#define NCH (NN / TILE)                 // 32 tile-chunks per side
#define NTRI (NCH * (NCH + 1) / 2)      // 528 upper-triangle blocks
#define NSTEP (DD / 32)                 // 16 K-steps

typedef unsigned short u16;
typedef __attribute__((ext_vector_type(4))) float f32x4;
typedef __attribute__((ext_vector_type(8))) short bf16x8;

// ws layout (bytes):
#define OFF_DVAL ((size_t)NN * DD * 2)                 // xbf: NN*DD u16
#define OFF_DINC (OFF_DVAL + (size_t)NN * 4)           // exact diag f32
#define OFF_HIST (OFF_DINC + (size_t)NN * 4)           // include flag f32
#define OFF_LRP  (OFF_HIST + 256 * 4)                  // class histogram i32
#define OFF_PART (OFF_LRP + 16 * 2 * 4)                // last-row partials
#define OFF_BS   (OFF_PART + (size_t)NCH * NN * 2 * 4) // per-chunk {pl,nl}
// OFF_BS: 16 blocks x {loss,inv} f64

__device__ __forceinline__ float softplus_fast(float z) {
  // ln(1+e^z); z in [-63, 23] here -> no overflow; 2 native transcendentals.
  return __logf(1.0f + __expf(z));
}

// ---------------------------------------------------------------------------
// prep (3 roles by blockIdx):
//   [0, NN/4):   x -> bf16 + exact f64 row sum-of-squares (diag decision)
//   NN/4:        class histogram (LDS int atomics = deterministic)
//   NN/4+1 ...:  last-row (4095) f32 sim partial sums {ss, ns}
__global__ __launch_bounds__(256) void prep_kernel(
    const float* __restrict__ x, const int* __restrict__ tg,
    u16* __restrict__ xbf, float* __restrict__ dval, float* __restrict__ dinc,
    int* __restrict__ hist, float* __restrict__ lrp) {
  const int bid = blockIdx.x;
  const int t = threadIdx.x;
  if (bid < NN / 4) {
    const int wid = t >> 6, lane = t & 63;
    const int row = bid * 4 + wid;
    const float* xr = x + (size_t)row * DD;
    u16* xb = xbf + (size_t)row * DD;
    double s = 0.0;
#pragma unroll
    for (int c = 0; c < DD / 64; ++c) {
      float v = xr[c * 64 + lane];
      s += (double)v * (double)v;
      __hip_bfloat16 b = __float2bfloat16(v);
      xb[c * 64 + lane] = *reinterpret_cast<const u16*>(&b);
    }
#pragma unroll
    for (int m = 32; m; m >>= 1) s += __shfl_xor(s, m, 64);
    if (lane == 0) {
      float sf = (float)s;
      dval[row] = sf;
      dinc[row] = (sf < 1.0f) ? 1.0f : 0.0f;  // ref: pos includes diag iff sim<1
    }
  } else if (bid == NN / 4) {
    __shared__ int h[256];
    h[t] = 0;
    __syncthreads();
    const int base = t * (NN / 256);
#pragma unroll
    for (int k = 0; k < NN / 256; ++k) atomicAdd(&h[tg[base + k]], 1);
    __syncthreads();
    hist[t] = h[t];
  } else {
    const int b = bid - (NN / 4 + 1);
    const int j = b * 256 + t;
    const int tl = tg[NN - 1];
    const f32x4* xr = (const f32x4*)(x + (size_t)(NN - 1) * DD);
    const f32x4* xj = (const f32x4*)(x + (size_t)j * DD);
    f32x4 av = {0.f, 0.f, 0.f, 0.f};
#pragma unroll 4
    for (int k = 0; k < DD / 4; ++k) av += xr[k] * xj[k];
    const float sim = av[0] + av[1] + av[2] + av[3];
    const bool same = (tg[j] == tl);
    float ss = (same && j != NN - 1) ? sim : 0.0f;
    float ns = !same ? sim : 0.0f;
#pragma unroll
    for (int m = 32; m; m >>= 1) {
      ss += __shfl_xor(ss, m, 64);
      ns += __shfl_xor(ns, m, 64);
    }
    __shared__ float r2[2][4];
    if ((t & 63) == 0) { r2[0][t >> 6] = ss; r2[1][t >> 6] = ns; }
    __syncthreads();
    if (t == 0) {
      lrp[b * 2 + 0] = r2[0][0] + r2[0][1] + r2[0][2] + r2[0][3];
      lrp[b * 2 + 1] = r2[1][0] + r2[1][1] + r2[1][2] + r2[1][3];
    }
  }
}

// ---------------------------------------------------------------------------
// main: upper-triangle 128x128 tiles. NO LDS staging, NO K-loop barriers:
// each wave loads its MFMA fragments straight from global (L2-resident,
// each wave-load = 16 full 64B lines) with a 2-deep register pipeline.
// Off-diagonal blocks emit BOTH row sums (tile bi) and column sums (tile bj,
// symmetry). One writer per (chunk,row) slot -> deterministic.
__global__ __launch_bounds__(256) void sim_kernel(
    const u16* __restrict__ xbf, const int* __restrict__ tg,
    float* __restrict__ part) {
  __shared__ float red[2][TILE][2];    // row sums, split by wC
  __shared__ float redc[2][TILE][2];   // col sums, split by wR

  // triangular decode: bi <= bj
  int l = blockIdx.x, bi = 0, span = NCH;
  while (l >= span) { l -= span; ++bi; --span; }
  const int bj = bi + l;
  const bool offdiag = (bi != bj);

  const int t = threadIdx.x;
  const int lane = t & 63, wid = t >> 6;
  const int wR = wid >> 1, wC = wid & 1;          // 2x2 wave grid, 64x64 each
  const int q = lane >> 4, lr = lane & 15;
  const int rowBase = bi * TILE, colBase = bj * TILE;

  // per-lane fragment base: row (base + m*16 + lr), k-offset q*8
  const u16* aB = xbf + (size_t)(rowBase + wR * 64 + lr) * DD + q * 8;
  const u16* bB = xbf + (size_t)(colBase + wC * 64 + lr) * DD + q * 8;

  f32x4 acc[4][4] = {};
  bf16x8 a0[4], b0[4], a1[4], b1[4];

#define LDF(A, B, kb)                                                        \
  do {                                                                       \
    _Pragma("unroll")                                                        \
    for (int m = 0; m < 4; ++m) {                                            \
      A[m] = *reinterpret_cast<const bf16x8*>(aB + (size_t)(m * 16) * DD + (kb)); \
      B[m] = *reinterpret_cast<const bf16x8*>(bB + (size_t)(m * 16) * DD + (kb)); \
    }                                                                        \
  } while (0)

#define MM(A, B)                                                             \
  do {                                                                       \
    _Pragma("unroll")                                                        \
    for (int m = 0; m < 4; ++m)                                              \
      _Pragma("unroll")                                                      \
      for (int n = 0; n < 4; ++n)                                            \
        acc[m][n] =                                                          \
            __builtin_amdgcn_mfma_f32_16x16x32_bf16(A[m], B[n], acc[m][n], 0, 0, 0); \
  } while (0)

  LDF(a0, b0, 0);
#pragma unroll 1
  for (int s = 0; s < NSTEP - 2; s += 2) {
    LDF(a1, b1, (s + 1) * 32);   // prefetch step s+1 while computing s
    MM(a0, b0);
    LDF(a0, b0, (s + 2) * 32);   // prefetch step s+2 while computing s+1
    MM(a1, b1);
  }
  LDF(a1, b1, (NSTEP - 1) * 32);
  MM(a0, b0);
  MM(a1, b1);
#undef LDF
#undef MM

  // epilogue: C/D layout col=lane&15, row=(lane>>4)*4+j (m89-verified).
  int tc[4];
#pragma unroll
  for (int n = 0; n < 4; ++n) tc[n] = tg[colBase + wC * 64 + n * 16 + lr];

  float colP[4] = {0.f, 0.f, 0.f, 0.f}, colN[4] = {0.f, 0.f, 0.f, 0.f};

#pragma unroll
  for (int m = 0; m < 4; ++m) {
#pragma unroll
    for (int j = 0; j < 4; ++j) {
      const int rloc = wR * 64 + m * 16 + q * 4 + j;
      const int ri = rowBase + rloc;
      const int trr = tg[ri];
      float pl = 0.f, nl = 0.f;
#pragma unroll
      for (int n = 0; n < 4; ++n) {
        const float sim = acc[m][n][j];
        const int cj = colBase + wC * 64 + n * 16 + lr;
        const bool same = (trr == tc[n]);
        const float c = same ? -2.0f : 40.0f;
        const float sp = softplus_fast(c * (sim - 0.5f));
        const float pv = (same && (ri != cj)) ? sp : 0.0f;  // diag analytic
        const float nv = same ? 0.0f : sp;
        pl += pv; nl += nv;
        colP[n] += pv; colN[n] += nv;
      }
#pragma unroll
      for (int s = 8; s; s >>= 1) {
        pl += __shfl_xor(pl, s, 64);
        nl += __shfl_xor(nl, s, 64);
      }
      if (lr == 0) { red[wC][rloc][0] = pl; red[wC][rloc][1] = nl; }
    }
  }

  if (offdiag) {
#pragma unroll
    for (int n = 0; n < 4; ++n) {
      colP[n] += __shfl_xor(colP[n], 16, 64);
      colP[n] += __shfl_xor(colP[n], 32, 64);
      colN[n] += __shfl_xor(colN[n], 16, 64);
      colN[n] += __shfl_xor(colN[n], 32, 64);
      if (q == 0) {
        const int cloc = wC * 64 + n * 16 + lr;
        redc[wR][cloc][0] = colP[n];
        redc[wR][cloc][1] = colN[n];
      }
    }
  }
  __syncthreads();

  if (t < TILE * 2) {
    const int row = t >> 1, v = t & 1;
    // row sums -> tile bi, chunk bj
    part[((size_t)bj * NN + (rowBase + row)) * 2 + v] =
        red[0][row][v] + red[1][row][v];
    // col sums -> tile bj, chunk bi (symmetry)
    if (offdiag) {
      part[((size_t)bi * NN + (colBase + row)) * 2 + v] =
          redc[0][row][v] + redc[1][row][v];
    }
  }
}

// ---------------------------------------------------------------------------
// finalize 1: per-row combine over 32 chunks + analytic diagonal + histogram
// counts; block-level f64 tree reduce -> 16 partials. Row 4095 emits
// last_pos/last_neg from the f32 partials.
__global__ __launch_bounds__(256) void fin1_kernel(
    const float* __restrict__ part, const float* __restrict__ dval,
    const float* __restrict__ dinc, const int* __restrict__ hist,
    const int* __restrict__ tg, const float* __restrict__ lrp,
    double* __restrict__ bsums, float* __restrict__ out) {
  const int t = threadIdx.x;
  const int r = blockIdx.x * 256 + t;
  float pl = 0.f, nl = 0.f;
  for (int c = 0; c < NCH; ++c) {
    const float* p = part + ((size_t)c * NN + r) * 2;
    pl += p[0]; nl += p[1];
  }
  const float inc = dinc[r], dv = dval[r];
  const float scnt = (float)(hist[tg[r]] - 1);   // off-diag same-class count
  const float pos_cnt = scnt + inc;
  const float pos_sum = pl + inc * softplus_fast(1.0f - 2.0f * dv);
  const float pos_loss = pos_sum / fmaxf(pos_cnt, 1.0f);
  const float neg_cnt = 4095.0f - scnt;
  const float neg_loss = nl / fmaxf(neg_cnt, 1.0f);
  const bool valid = neg_cnt > 0.0f;

  __shared__ double sl[256];
  __shared__ double si[256];
  sl[t] = valid ? (double)(pos_loss + neg_loss) : 0.0;
  si[t] = valid ? 0.0 : 1.0;
  __syncthreads();
  for (int s = 128; s; s >>= 1) {
    if (t < s) { sl[t] += sl[t + s]; si[t] += si[t + s]; }
    __syncthreads();
  }
  if (t == 0) { bsums[blockIdx.x * 2] = sl[0]; bsums[blockIdx.x * 2 + 1] = si[0]; }

  if (r == NN - 1) {
    float ss = 0.f, ns = 0.f;
    for (int c = 0; c < 16; ++c) { ss += lrp[c * 2]; ns += lrp[c * 2 + 1]; }
    out[2] = (ss + inc * dv) / fmaxf(pos_cnt, 1.0f);
    out[3] = ns / fmaxf(neg_cnt, 1.0f);
  }
}

// finalize 2: tiny — sum 16 block partials.
__global__ __launch_bounds__(64) void fin2_kernel(
    const double* __restrict__ bsums, float* __restrict__ out) {
  if (threadIdx.x == 0) {
    double l = 0.0, iv = 0.0;
    for (int b = 0; b < NN / 256; ++b) { l += bsums[b * 2]; iv += bsums[b * 2 + 1]; }
    out[0] = (float)(l / NN);
    out[1] = (float)(iv / NN);
  }
}

extern "C" void kernel_launch(void* const* d_in, const int* in_sizes, int n_in,
                              void* d_out, int out_size, void* d_ws, size_t ws_size,
                              hipStream_t stream) {
  const float* x = (const float*)d_in[0];
  const int* tg = (const int*)d_in[1];
  float* out = (float*)d_out;
  char* ws = (char*)d_ws;

  u16*    xbf  = (u16*)ws;
  float*  dval = (float*)(ws + OFF_DVAL);
  float*  dinc = (float*)(ws + OFF_DINC);
  int*    hist = (int*)(ws + OFF_HIST);
  float*  lrp  = (float*)(ws + OFF_LRP);
  float*  part = (float*)(ws + OFF_PART);
  double* bs   = (double*)(ws + OFF_BS);

  prep_kernel<<<NN / 4 + 1 + 16, 256, 0, stream>>>(x, tg, xbf, dval, dinc, hist, lrp);
  sim_kernel<<<NTRI, 256, 0, stream>>>(xbf, tg, part);
  fin1_kernel<<<NN / 256, 256, 0, stream>>>(part, dval, dinc, hist, tg, lrp, bs, out);
  fin2_kernel<<<1, 64, 0, stream>>>(bs, out);
}

// Round 6
// 53.236 us; speedup vs baseline: 1.6742x; 1.6742x over previous
//
#include <hip/hip_runtime.h>
#include <hip/hip_bf16.h>

#define NN 4096
#define DD 512
#define TILE 128
#define NCH (NN / TILE)                 // 32 tile-chunks per side
#define NTRI (NCH * (NCH + 1) / 2)      // 528 upper-triangle blocks
#define NSTEP (DD / 32)                 // 16 K-steps

typedef unsigned short u16;
typedef __attribute__((ext_vector_type(4))) float f32x4;
typedef __attribute__((ext_vector_type(8))) short bf16x8;

// ws layout (bytes):
#define OFF_DVAL ((size_t)NN * DD * 2)                 // xbf: NN*DD u16
#define OFF_DINC (OFF_DVAL + (size_t)NN * 4)           // exact diag f32
#define OFF_HIST (OFF_DINC + (size_t)NN * 4)           // include flag f32
#define OFF_LRP  (OFF_HIST + 256 * 4)                  // class histogram i32
#define OFF_PART (OFF_LRP + (size_t)NCH * 2 * 4)       // last-row partials (32 blk x {ss,ns})
#define OFF_BS   (OFF_PART + (size_t)NCH * NN * 2 * 4) // per-chunk {pl,nl}
// OFF_BS: 16 blocks x {loss,inv} f64

__device__ __forceinline__ float softplus_fast(float z) {
  // ln(1+e^z); z in [-63, 24] here -> no overflow; 2 native transcendentals.
  return __logf(1.0f + __expf(z));
}

__device__ __forceinline__ void gload_lds16(const u16* g, void* l) {
  __builtin_amdgcn_global_load_lds(
      (const __attribute__((address_space(1))) void*)g,
      (__attribute__((address_space(3))) void*)l, 16, 0, 0);
}

// ---------------------------------------------------------------------------
// prep (2 roles by blockIdx):
//   [0, NN/4):   x -> bf16 + exact f64 row sum-of-squares (diag decision)
//   NN/4:        class histogram (LDS int atomics = deterministic)
__global__ __launch_bounds__(256) void prep_kernel(
    const float* __restrict__ x, const int* __restrict__ tg,
    u16* __restrict__ xbf, float* __restrict__ dval, float* __restrict__ dinc,
    int* __restrict__ hist) {
  const int bid = blockIdx.x;
  const int t = threadIdx.x;
  if (bid < NN / 4) {
    const int wid = t >> 6, lane = t & 63;
    const int row = bid * 4 + wid;
    const float* xr = x + (size_t)row * DD;
    u16* xb = xbf + (size_t)row * DD;
    double s = 0.0;
#pragma unroll
    for (int c = 0; c < DD / 64; ++c) {
      float v = xr[c * 64 + lane];
      s += (double)v * (double)v;
      __hip_bfloat16 b = __float2bfloat16(v);
      xb[c * 64 + lane] = *reinterpret_cast<const u16*>(&b);
    }
#pragma unroll
    for (int m = 32; m; m >>= 1) s += __shfl_xor(s, m, 64);
    if (lane == 0) {
      float sf = (float)s;
      dval[row] = sf;
      dinc[row] = (sf < 1.0f) ? 1.0f : 0.0f;  // ref: pos includes diag iff sim<1
    }
  } else {
    __shared__ int h[256];
    h[t] = 0;
    __syncthreads();
    const int base = t * (NN / 256);
#pragma unroll
    for (int k = 0; k < NN / 256; ++k) atomicAdd(&h[tg[base + k]], 1);
    __syncthreads();
    hist[t] = h[t];
  }
}

// ---------------------------------------------------------------------------
// main: upper-triangle 128x128 tiles, dbuf LDS staging. Cheap epilogue:
//   negatives: softplus(40(sim-.5)) == exp(40 sim - 20) for all real data
//   (z <= -8); exactness guard for z > -8. Positives handled in a
//   nearly-always-skipped exec-masked branch. Row reduction via LDS
//   transpose (ds_write_b128) instead of 256 shuffles/thread.
// Off-diagonal blocks also emit column sums (symmetry). bj==NCH-1 blocks
// extract last-row (4095) {pos_sim,neg_sim} partials from acc directly.
__global__ __launch_bounds__(256) void sim_kernel(
    const u16* __restrict__ xbf, const int* __restrict__ tg,
    float* __restrict__ part, float* __restrict__ lrp) {
  // union region: K-loop staging (32768 B) / epilogue red2 [2][32][132] f32
  __shared__ __align__(16) char smem[33792];
  __shared__ float redc[2][TILE][2];   // col sums, split by wR
  __shared__ float lrr[2][2];          // last-row partials, [wR][var]

  // triangular decode: bi <= bj
  int l = blockIdx.x, bi = 0, span = NCH;
  while (l >= span) { l -= span; ++bi; --span; }
  const int bj = bi + l;
  const bool offdiag = (bi != bj);

  const int t = threadIdx.x;
  const int lane = t & 63, wid = t >> 6;
  const int wR = wid >> 1, wC = wid & 1;          // 2x2 wave grid, 64x64 each
  const int q = lane >> 4, lr = lane & 15;
  const int rowBase = bi * TILE, colBase = bj * TILE;

  const int r0 = t >> 2;            // 0..63
  const int kk = (t & 3) * 8;       // 0,8,16,24
  const u16* gA0 = xbf + (size_t)(rowBase + r0) * DD + kk;
  const u16* gB0 = xbf + (size_t)(colBase + r0) * DD + kk;
  u16* sA = (u16*)smem;             // sA[buf][4096], sB[buf][4096]
  u16* sB = (u16*)smem + 8192;

#define STAGE(kb, b)                                            \
  do {                                                          \
    char* lA_ = (char*)(sA + (b) * 4096) + wid * 1024;          \
    char* lB_ = (char*)(sB + (b) * 4096) + wid * 1024;          \
    gload_lds16(gA0 + (kb), lA_);                               \
    gload_lds16(gA0 + (kb) + 64 * DD, lA_ + 4096);              \
    gload_lds16(gB0 + (kb), lB_);                               \
    gload_lds16(gB0 + (kb) + 64 * DD, lB_ + 4096);              \
  } while (0)

  f32x4 acc[4][4] = {};

  STAGE(0, 0);
  __syncthreads();

#pragma unroll 2
  for (int s = 0; s < NSTEP; ++s) {
    const int cur = s & 1;
    if (s + 1 < NSTEP) STAGE((s + 1) * 32, cur ^ 1);

    bf16x8 af[4], bg[4];
#pragma unroll
    for (int m = 0; m < 4; ++m) {
      af[m] = *reinterpret_cast<const bf16x8*>(&sA[cur * 4096 + (wR * 64 + m * 16 + lr) * 32 + q * 8]);
      bg[m] = *reinterpret_cast<const bf16x8*>(&sB[cur * 4096 + (wC * 64 + m * 16 + lr) * 32 + q * 8]);
    }
#pragma unroll
    for (int m = 0; m < 4; ++m)
#pragma unroll
      for (int n = 0; n < 4; ++n)
        acc[m][n] = __builtin_amdgcn_mfma_f32_16x16x32_bf16(af[m], bg[n], acc[m][n], 0, 0, 0);
    __syncthreads();   // also guards smem reuse by epilogue
  }
#undef STAGE

  // ---- epilogue. C/D layout: col=lane&15, row=(lane>>4)*4+j (m89-verified).
  int tc[4];
#pragma unroll
  for (int n = 0; n < 4; ++n) tc[n] = tg[colBase + wC * 64 + n * 16 + lr];

  float plv[4][4], nlv[4][4];
#pragma unroll
  for (int m = 0; m < 4; ++m)
#pragma unroll
    for (int j = 0; j < 4; ++j) { plv[m][j] = 0.f; nlv[m][j] = 0.f; }
  float colP[4] = {0.f, 0.f, 0.f, 0.f}, colN[4] = {0.f, 0.f, 0.f, 0.f};

#pragma unroll
  for (int m = 0; m < 4; ++m) {
#pragma unroll
    for (int j = 0; j < 4; ++j) {
      const int ri = rowBase + wR * 64 + m * 16 + q * 4 + j;
      const int trr = tg[ri];
#pragma unroll
      for (int n = 0; n < 4; ++n) {
        const float sim = acc[m][n][j];
        const float z = __fmaf_rn(40.0f, sim, -20.0f);
        float e = __expf(z);               // == softplus(z) for z <= -8
        if (z > -8.0f) e = __logf(1.0f + e);  // exactness guard (never taken
                                              // for real negatives; harmless
                                              // for positives: masked below)
        const bool same = (trr == tc[n]);
        const float t0 = same ? 0.0f : e;
        nlv[m][j] += t0;
        colN[n] += t0;
        if (same) {                        // rare: ~0.25 lanes per check
          const int cj = colBase + wC * 64 + n * 16 + lr;
          if (ri != cj) {                  // diag handled analytically
            const float sp = softplus_fast(__fmaf_rn(-2.0f, sim, 1.0f));
            plv[m][j] += sp;
            colP[n] += sp;
          }
        }
      }
    }
  }

  // row-partial transpose into LDS: red2[var][slot 32][132] f32
  float* red2f = (float*)smem;
  const int slot = wC * 16 + lr;
#pragma unroll
  for (int m = 0; m < 4; ++m) {
    const int row0 = wR * 64 + m * 16 + q * 4;
    f32x4 pv = {plv[m][0], plv[m][1], plv[m][2], plv[m][3]};
    f32x4 nv = {nlv[m][0], nlv[m][1], nlv[m][2], nlv[m][3]};
    *reinterpret_cast<f32x4*>(&red2f[(0 * 32 + slot) * 132 + row0]) = pv;
    *reinterpret_cast<f32x4*>(&red2f[(1 * 32 + slot) * 132 + row0]) = nv;
  }

  // column sums (only used by offdiag blocks): 2-level shuffle + LDS
  if (offdiag) {
#pragma unroll
    for (int n = 0; n < 4; ++n) {
      colP[n] += __shfl_xor(colP[n], 16, 64);
      colP[n] += __shfl_xor(colP[n], 32, 64);
      colN[n] += __shfl_xor(colN[n], 16, 64);
      colN[n] += __shfl_xor(colN[n], 32, 64);
      if (q == 0) {
        const int cloc = wC * 64 + n * 16 + lr;
        redc[wR][cloc][0] = colP[n];
        redc[wR][cloc][1] = colN[n];
      }
    }
  }

  // last-row (4095) sim partials from acc: blocks with bj == NCH-1.
  if (bj == NCH - 1) {
    const int tgl = tc[3];  // only meaningful where lr==15 (col 4095)
    float ssl = 0.f, nsl = 0.f;
    const bool isc = (wC == 1) && (lr == 15);
#pragma unroll
    for (int m = 0; m < 4; ++m)
#pragma unroll
      for (int j = 0; j < 4; ++j) {
        const int ri = rowBase + wR * 64 + m * 16 + q * 4 + j;
        const float sim = acc[m][3][j];
        const bool same = (tg[ri] == tgl);
        ssl += (isc && same && ri != NN - 1) ? sim : 0.f;
        nsl += (isc && !same) ? sim : 0.f;
      }
#pragma unroll
    for (int mm = 32; mm; mm >>= 1) {
      ssl += __shfl_xor(ssl, mm, 64);
      nsl += __shfl_xor(nsl, mm, 64);
    }
    if (wC == 1 && lane == 0) { lrr[wR][0] = ssl; lrr[wR][1] = nsl; }
  }
  __syncthreads();

  // final reduce: thread (var,row) sums 32 slots, writes part directly.
  {
    const int var = t >> 7, row = t & 127;
    float s0 = 0.f, s1 = 0.f, s2 = 0.f, s3 = 0.f;
#pragma unroll
    for (int sl = 0; sl < 32; sl += 4) {
      s0 += red2f[(var * 32 + sl + 0) * 132 + row];
      s1 += red2f[(var * 32 + sl + 1) * 132 + row];
      s2 += red2f[(var * 32 + sl + 2) * 132 + row];
      s3 += red2f[(var * 32 + sl + 3) * 132 + row];
    }
    part[((size_t)bj * NN + (rowBase + row)) * 2 + var] = (s0 + s1) + (s2 + s3);
  }
  if (offdiag) {
    const int row = t >> 1, v = t & 1;
    part[((size_t)bi * NN + (colBase + row)) * 2 + v] =
        redc[0][row][v] + redc[1][row][v];
  }
  if (bj == NCH - 1 && t == 0) {
    lrp[bi * 2 + 0] = lrr[0][0] + lrr[1][0];
    lrp[bi * 2 + 1] = lrr[0][1] + lrr[1][1];
  }
}

// ---------------------------------------------------------------------------
// finalize 1: per-row combine over 32 chunks + analytic diagonal + histogram
// counts; block-level f64 tree reduce -> 16 partials. Row 4095 emits
// last_pos/last_neg from the sim-block partials.
__global__ __launch_bounds__(256) void fin1_kernel(
    const float* __restrict__ part, const float* __restrict__ dval,
    const float* __restrict__ dinc, const int* __restrict__ hist,
    const int* __restrict__ tg, const float* __restrict__ lrp,
    double* __restrict__ bsums, float* __restrict__ out) {
  const int t = threadIdx.x;
  const int r = blockIdx.x * 256 + t;
  float pl = 0.f, nl = 0.f;
  for (int c = 0; c < NCH; ++c) {
    const float* p = part + ((size_t)c * NN + r) * 2;
    pl += p[0]; nl += p[1];
  }
  const float inc = dinc[r], dv = dval[r];
  const float scnt = (float)(hist[tg[r]] - 1);   // off-diag same-class count
  const float pos_cnt = scnt + inc;
  const float pos_sum = pl + inc * softplus_fast(__fmaf_rn(-2.0f, dv, 1.0f));
  const float pos_loss = pos_sum / fmaxf(pos_cnt, 1.0f);
  const float neg_cnt = 4095.0f - scnt;
  const float neg_loss = nl / fmaxf(neg_cnt, 1.0f);
  const bool valid = neg_cnt > 0.0f;

  __shared__ double sl[256];
  __shared__ double si[256];
  sl[t] = valid ? (double)(pos_loss + neg_loss) : 0.0;
  si[t] = valid ? 0.0 : 1.0;
  __syncthreads();
  for (int s = 128; s; s >>= 1) {
    if (t < s) { sl[t] += sl[t + s]; si[t] += si[t + s]; }
    __syncthreads();
  }
  if (t == 0) { bsums[blockIdx.x * 2] = sl[0]; bsums[blockIdx.x * 2 + 1] = si[0]; }

  if (r == NN - 1) {
    float ss = 0.f, ns = 0.f;
    for (int c = 0; c < NCH; ++c) { ss += lrp[c * 2]; ns += lrp[c * 2 + 1]; }
    out[2] = (ss + inc * dv) / fmaxf(pos_cnt, 1.0f);
    out[3] = ns / fmaxf(neg_cnt, 1.0f);
  }
}

// finalize 2: tiny — sum 16 block partials.
__global__ __launch_bounds__(64) void fin2_kernel(
    const double* __restrict__ bsums, float* __restrict__ out) {
  if (threadIdx.x == 0) {
    double l = 0.0, iv = 0.0;
    for (int b = 0; b < NN / 256; ++b) { l += bsums[b * 2]; iv += bsums[b * 2 + 1]; }
    out[0] = (float)(l / NN);
    out[1] = (float)(iv / NN);
  }
}

extern "C" void kernel_launch(void* const* d_in, const int* in_sizes, int n_in,
                              void* d_out, int out_size, void* d_ws, size_t ws_size,
                              hipStream_t stream) {
  const float* x = (const float*)d_in[0];
  const int* tg = (const int*)d_in[1];
  float* out = (float*)d_out;
  char* ws = (char*)d_ws;

  u16*    xbf  = (u16*)ws;
  float*  dval = (float*)(ws + OFF_DVAL);
  float*  dinc = (float*)(ws + OFF_DINC);
  int*    hist = (int*)(ws + OFF_HIST);
  float*  lrp  = (float*)(ws + OFF_LRP);
  float*  part = (float*)(ws + OFF_PART);
  double* bs   = (double*)(ws + OFF_BS);

  prep_kernel<<<NN / 4 + 1, 256, 0, stream>>>(x, tg, xbf, dval, dinc, hist);
  sim_kernel<<<NTRI, 256, 0, stream>>>(xbf, tg, part, lrp);
  fin1_kernel<<<NN / 256, 256, 0, stream>>>(part, dval, dinc, hist, tg, lrp, bs, out);
  fin2_kernel<<<1, 64, 0, stream>>>(bs, out);
}